// Round 5
// baseline (40.746 us; speedup 1.0000x reference)
//
#include <hip/hip_runtime.h>
#include <hip/hip_bf16.h>

#define DIM 128
#define ROW 16
#define ROWS_PER_BLOCK 4   // 256 threads = 4 waves, one row per 64-lane wave

// One 64-lane wave per batch row. Lane holds floats [lane*2, lane*2+2) of each
// gathered 128-dim embedding (float2 = 8B/lane, 512B/row per instruction,
// fully coalesced). Fused finalization: last block to arrive reduces the
// per-block partials in fixed order (deterministic) and writes the mean.
__global__ __launch_bounds__(256) void n2v_fused_kernel(
    const float* __restrict__ X,
    const int* __restrict__ rw,
    const int* __restrict__ lp,
    float* __restrict__ partial,
    unsigned int* __restrict__ counter,
    float* __restrict__ out,
    int batch)
{
    const int tid  = threadIdx.x;
    const int lane = tid & 63;
    const int wv   = tid >> 6;
    const int row  = blockIdx.x * ROWS_PER_BLOCK + wv;
    const bool valid = (row < batch);

    const int l = *lp;
    const int W = l + 1;                     // 6

    const int* walk = rw + (valid ? row : 0) * ROW;

    // 16 walk indices via 4 broadcast int4 loads (one 64B line).
    int idx[ROW];
    {
        int4 t0 = *reinterpret_cast<const int4*>(walk);
        int4 t1 = *reinterpret_cast<const int4*>(walk + 4);
        int4 t2 = *reinterpret_cast<const int4*>(walk + 8);
        int4 t3 = *reinterpret_cast<const int4*>(walk + 12);
        idx[0]=t0.x; idx[1]=t0.y; idx[2]=t0.z; idx[3]=t0.w;
        idx[4]=t1.x; idx[5]=t1.y; idx[6]=t1.z; idx[7]=t1.w;
        idx[8]=t2.x; idx[9]=t2.y; idx[10]=t2.z; idx[11]=t2.w;
        idx[12]=t3.x; idx[13]=t3.y; idx[14]=t3.z; idx[15]=t3.w;
    }

    // Gather: 16 float2 loads (512B/row/instruction, coalesced), all in flight.
    float2 e[ROW];
    #pragma unroll
    for (int j = 0; j < ROW; ++j) {
        e[j] = *reinterpret_cast<const float2*>(
            X + (size_t)idx[j] * DIM + lane * 2);
    }

    const float2 s = e[0];

    float p[ROW];
    #pragma unroll
    for (int j = 0; j < ROW; ++j)
        p[j] = e[j].x * s.x + e[j].y * s.y;

    // Value-halving butterfly over bits 0..3 (15 shfls); lane ends with the
    // 16-lane-group partial of dot[brev4(lane&15)].
    {
        { // 16 -> 8 (xor 1)
            const bool sel = (lane >> 0) & 1;
            float np[8];
            #pragma unroll
            for (int i = 0; i < 8; ++i) {
                float send = sel ? p[i] : p[i + 8];
                float recv = __shfl_xor(send, 1, 64);
                np[i] = (sel ? p[i + 8] : p[i]) + recv;
            }
            #pragma unroll
            for (int i = 0; i < 8; ++i) p[i] = np[i];
        }
        { // 8 -> 4 (xor 2)
            const bool sel = (lane >> 1) & 1;
            float np[4];
            #pragma unroll
            for (int i = 0; i < 4; ++i) {
                float send = sel ? p[i] : p[i + 4];
                float recv = __shfl_xor(send, 2, 64);
                np[i] = (sel ? p[i + 4] : p[i]) + recv;
            }
            #pragma unroll
            for (int i = 0; i < 4; ++i) p[i] = np[i];
        }
        { // 4 -> 2 (xor 4)
            const bool sel = (lane >> 2) & 1;
            float np[2];
            #pragma unroll
            for (int i = 0; i < 2; ++i) {
                float send = sel ? p[i] : p[i + 2];
                float recv = __shfl_xor(send, 4, 64);
                np[i] = (sel ? p[i + 2] : p[i]) + recv;
            }
            p[0] = np[0]; p[1] = np[1];
        }
        { // 2 -> 1 (xor 8)
            const bool sel = (lane >> 3) & 1;
            float send = sel ? p[0] : p[1];
            float recv = __shfl_xor(send, 8, 64);
            p[0] = (sel ? p[1] : p[0]) + recv;
        }
    }
    // Finish across the four 16-lane groups (bits 4,5).
    p[0] += __shfl_xor(p[0], 16, 64);
    p[0] += __shfl_xor(p[0], 32, 64);

    const int g = lane & 15;
    const int j = ((g & 1) << 3) | ((g & 2) << 1) | ((g & 4) >> 1) | ((g & 8) >> 3);
    const float dot = p[0];

    float numer_c = 0.f, den_c = 0.f;
    if ((lane >> 4) == 0) {
        numer_c = (j >= 1 && j < W) ? dot : 0.f;
        int dup = 0;
        if (j < W) {
            const int idxj = walk[j];        // L1-hit broadcast line
            #pragma unroll
            for (int i = 0; i < ROW - 1; ++i)
                dup |= (i < j) & (idx[i] == idxj);
        }
        den_c = dup ? 0.f : expf(dot);
    }

    #pragma unroll
    for (int d = 1; d < 64; d <<= 1) {
        numer_c += __shfl_xor(numer_c, d, 64);
        den_c   += __shfl_xor(den_c, d, 64);
    }

    __shared__ float sm[ROWS_PER_BLOCK];
    __shared__ int s_last;
    if (lane == 0)
        sm[wv] = valid ? ((float)l * logf(den_c) - numer_c) : 0.f;
    __syncthreads();
    if (tid == 0) {
        const float bp = sm[0] + sm[1] + sm[2] + sm[3];
        // Publish partial (device scope), then arrive at the counter.
        __hip_atomic_store(&partial[blockIdx.x], bp,
                           __ATOMIC_RELEASE, __HIP_MEMORY_SCOPE_AGENT);
        unsigned int old = __hip_atomic_fetch_add(counter, 1u,
                           __ATOMIC_ACQ_REL, __HIP_MEMORY_SCOPE_AGENT);
        s_last = (old == (unsigned int)gridDim.x - 1u) ? 1 : 0;
    }
    __syncthreads();

    // Last-arriving block: deterministic fixed-order reduce -> mean.
    if (s_last) {
        const int nblk = gridDim.x;
        float acc = 0.f;
        for (int i = tid; i < nblk; i += 256)
            acc += __hip_atomic_load(&partial[i],
                                     __ATOMIC_ACQUIRE, __HIP_MEMORY_SCOPE_AGENT);
        #pragma unroll
        for (int d = 1; d < 64; d <<= 1)
            acc += __shfl_xor(acc, d, 64);
        __shared__ float sr[4];
        if (lane == 0) sr[wv] = acc;
        __syncthreads();
        if (tid == 0)
            out[0] = (sr[0] + sr[1] + sr[2] + sr[3]) / (float)batch;
    }
}

extern "C" void kernel_launch(void* const* d_in, const int* in_sizes, int n_in,
                              void* d_out, int out_size, void* d_ws, size_t ws_size,
                              hipStream_t stream)
{
    const float* X  = (const float*)d_in[0];
    const int*   rw = (const int*)d_in[1];
    const int*   lp = (const int*)d_in[2];
    float* out = (float*)d_out;

    const int batch = in_sizes[1] / ROW;                              // 4096
    const int grid  = (batch + ROWS_PER_BLOCK - 1) / ROWS_PER_BLOCK;  // 1024

    float* partial = (float*)d_ws;                 // grid floats
    unsigned int* counter = (unsigned int*)((char*)d_ws + grid * sizeof(float));

    // Zero the arrival counter each call (graph-capturable memset node).
    hipMemsetAsync(counter, 0, sizeof(unsigned int), stream);

    n2v_fused_kernel<<<grid, 256, 0, stream>>>(X, rw, lp, partial, counter,
                                               out, batch);
}

// Round 6
// 20.450 us; speedup vs baseline: 1.9925x; 1.9925x over previous
//
#include <hip/hip_runtime.h>
#include <hip/hip_bf16.h>

#define DIM 128
#define ROW 16
#define ROWS_PER_BLOCK 8   // 512 threads = 8 waves, one row per 64-lane wave

// One 64-lane wave per batch row. Lane holds floats [lane*2, lane*2+2) of each
// gathered 128-dim embedding (float2 = 8B/lane, 512B/row per instruction,
// fully coalesced). Single dispatch: each block folds its 8 rows to one
// partial and does ONE relaxed device-scope atomicAdd into out[0] (no
// release/acquire -> no cross-XCD L2 writeback/invalidate storms).
__global__ __launch_bounds__(512, 4) void n2v_fused_kernel(
    const float* __restrict__ X,
    const int* __restrict__ rw,
    const int* __restrict__ lp,
    float* __restrict__ out,
    int batch)
{
    const int tid  = threadIdx.x;
    const int lane = tid & 63;
    const int wv   = tid >> 6;
    const int row  = blockIdx.x * ROWS_PER_BLOCK + wv;
    const bool valid = (row < batch);

    const int l = *lp;
    const int W = l + 1;                     // 6

    const int* walk = rw + (valid ? row : 0) * ROW;

    // 16 walk indices via 4 broadcast int4 loads (one 64B line).
    int idx[ROW];
    {
        int4 t0 = *reinterpret_cast<const int4*>(walk);
        int4 t1 = *reinterpret_cast<const int4*>(walk + 4);
        int4 t2 = *reinterpret_cast<const int4*>(walk + 8);
        int4 t3 = *reinterpret_cast<const int4*>(walk + 12);
        idx[0]=t0.x; idx[1]=t0.y; idx[2]=t0.z; idx[3]=t0.w;
        idx[4]=t1.x; idx[5]=t1.y; idx[6]=t1.z; idx[7]=t1.w;
        idx[8]=t2.x; idx[9]=t2.y; idx[10]=t2.z; idx[11]=t2.w;
        idx[12]=t3.x; idx[13]=t3.y; idx[14]=t3.z; idx[15]=t3.w;
    }

    // Gather: 16 float2 loads (512B/row/instruction, coalesced), all in flight.
    float2 e[ROW];
    #pragma unroll
    for (int j = 0; j < ROW; ++j) {
        e[j] = *reinterpret_cast<const float2*>(
            X + (size_t)idx[j] * DIM + lane * 2);
    }

    const float2 s = e[0];

    float p[ROW];
    #pragma unroll
    for (int j = 0; j < ROW; ++j)
        p[j] = e[j].x * s.x + e[j].y * s.y;

    // Value-halving butterfly over bits 0..3 (15 shfls); lane ends with the
    // 16-lane-group partial of dot[brev4(lane&15)].
    {
        { // 16 -> 8 (xor 1)
            const bool sel = (lane >> 0) & 1;
            float np[8];
            #pragma unroll
            for (int i = 0; i < 8; ++i) {
                float send = sel ? p[i] : p[i + 8];
                float recv = __shfl_xor(send, 1, 64);
                np[i] = (sel ? p[i + 8] : p[i]) + recv;
            }
            #pragma unroll
            for (int i = 0; i < 8; ++i) p[i] = np[i];
        }
        { // 8 -> 4 (xor 2)
            const bool sel = (lane >> 1) & 1;
            float np[4];
            #pragma unroll
            for (int i = 0; i < 4; ++i) {
                float send = sel ? p[i] : p[i + 4];
                float recv = __shfl_xor(send, 2, 64);
                np[i] = (sel ? p[i + 4] : p[i]) + recv;
            }
            #pragma unroll
            for (int i = 0; i < 4; ++i) p[i] = np[i];
        }
        { // 4 -> 2 (xor 4)
            const bool sel = (lane >> 2) & 1;
            float np[2];
            #pragma unroll
            for (int i = 0; i < 2; ++i) {
                float send = sel ? p[i] : p[i + 2];
                float recv = __shfl_xor(send, 4, 64);
                np[i] = (sel ? p[i + 2] : p[i]) + recv;
            }
            p[0] = np[0]; p[1] = np[1];
        }
        { // 2 -> 1 (xor 8)
            const bool sel = (lane >> 3) & 1;
            float send = sel ? p[0] : p[1];
            float recv = __shfl_xor(send, 8, 64);
            p[0] = (sel ? p[1] : p[0]) + recv;
        }
    }
    // Finish across the four 16-lane groups (bits 4,5).
    p[0] += __shfl_xor(p[0], 16, 64);
    p[0] += __shfl_xor(p[0], 32, 64);

    const int g = lane & 15;
    const int j = ((g & 1) << 3) | ((g & 2) << 1) | ((g & 4) >> 1) | ((g & 8) >> 3);
    const float dot = p[0];

    float numer_c = 0.f, den_c = 0.f;
    if ((lane >> 4) == 0) {
        numer_c = (j >= 1 && j < W) ? dot : 0.f;
        int dup = 0;
        if (j < W) {
            const int idxj = walk[j];        // L1-hit broadcast line
            #pragma unroll
            for (int i = 0; i < ROW - 1; ++i)
                dup |= (i < j) & (idx[i] == idxj);
        }
        den_c = dup ? 0.f : expf(dot);
    }

    #pragma unroll
    for (int d = 1; d < 64; d <<= 1) {
        numer_c += __shfl_xor(numer_c, d, 64);
        den_c   += __shfl_xor(den_c, d, 64);
    }

    // Per-wave loss -> LDS -> one atomicAdd per block (relaxed, device scope).
    __shared__ float sm[ROWS_PER_BLOCK];
    if (lane == 0)
        sm[wv] = valid ? ((float)l * logf(den_c) - numer_c) : 0.f;
    __syncthreads();
    if (tid == 0) {
        float bp = 0.f;
        #pragma unroll
        for (int i = 0; i < ROWS_PER_BLOCK; ++i) bp += sm[i];
        atomicAdd(out, bp * (1.0f / (float)batch));
    }
}

extern "C" void kernel_launch(void* const* d_in, const int* in_sizes, int n_in,
                              void* d_out, int out_size, void* d_ws, size_t ws_size,
                              hipStream_t stream)
{
    const float* X  = (const float*)d_in[0];
    const int*   rw = (const int*)d_in[1];
    const int*   lp = (const int*)d_in[2];
    float* out = (float*)d_out;

    const int batch = in_sizes[1] / ROW;                              // 4096
    const int grid  = (batch + ROWS_PER_BLOCK - 1) / ROWS_PER_BLOCK;  // 512

    // Zero the accumulator each call (tiny graph-capturable memset node).
    hipMemsetAsync(out, 0, sizeof(float), stream);

    n2v_fused_kernel<<<grid, 512, 0, stream>>>(X, rw, lp, out, batch);
}

// Round 7
// 16.373 us; speedup vs baseline: 2.4886x; 1.2490x over previous
//
#include <hip/hip_runtime.h>
#include <hip/hip_bf16.h>

#define DIM 128
#define ROW 16
#define ROWS_PER_BLOCK 4   // 256 threads = 4 waves, one row per 64-lane wave

// One 64-lane wave per batch row. Lane holds floats [lane*2, lane*2+2) of each
// gathered 128-dim embedding (float2 = 8B/lane, 512B/row per instruction,
// fully coalesced). Proven R3 structure: 13.0 us.
__global__ __launch_bounds__(256) void n2v_row_kernel(
    const float* __restrict__ X,
    const int* __restrict__ rw,
    const int* __restrict__ lp,
    float* __restrict__ partial,
    int batch)
{
    const int tid  = threadIdx.x;
    const int lane = tid & 63;
    const int wv   = tid >> 6;
    const int row  = blockIdx.x * ROWS_PER_BLOCK + wv;
    const bool valid = (row < batch);

    const int l = *lp;
    const int W = l + 1;                     // 6

    const int* walk = rw + (valid ? row : 0) * ROW;

    // 16 walk indices via 4 broadcast int4 loads (wave-uniform -> s_load path).
    int idx[ROW];
    {
        int4 t0 = *reinterpret_cast<const int4*>(walk);
        int4 t1 = *reinterpret_cast<const int4*>(walk + 4);
        int4 t2 = *reinterpret_cast<const int4*>(walk + 8);
        int4 t3 = *reinterpret_cast<const int4*>(walk + 12);
        idx[0]=t0.x; idx[1]=t0.y; idx[2]=t0.z; idx[3]=t0.w;
        idx[4]=t1.x; idx[5]=t1.y; idx[6]=t1.z; idx[7]=t1.w;
        idx[8]=t2.x; idx[9]=t2.y; idx[10]=t2.z; idx[11]=t2.w;
        idx[12]=t3.x; idx[13]=t3.y; idx[14]=t3.z; idx[15]=t3.w;
    }

    // Gather: 16 float2 loads (512B/row/instruction, coalesced), all in flight.
    float2 e[ROW];
    #pragma unroll
    for (int j = 0; j < ROW; ++j) {
        e[j] = *reinterpret_cast<const float2*>(
            X + (size_t)idx[j] * DIM + lane * 2);
    }

    const float2 s = e[0];

    float p[ROW];
    #pragma unroll
    for (int j = 0; j < ROW; ++j)
        p[j] = e[j].x * s.x + e[j].y * s.y;

    // Value-halving butterfly over bits 0..3 (15 shfls); lane ends with the
    // 16-lane-group partial of dot[brev4(lane&15)].
    {
        { // 16 -> 8 (xor 1)
            const bool sel = (lane >> 0) & 1;
            float np[8];
            #pragma unroll
            for (int i = 0; i < 8; ++i) {
                float send = sel ? p[i] : p[i + 8];
                float recv = __shfl_xor(send, 1, 64);
                np[i] = (sel ? p[i + 8] : p[i]) + recv;
            }
            #pragma unroll
            for (int i = 0; i < 8; ++i) p[i] = np[i];
        }
        { // 8 -> 4 (xor 2)
            const bool sel = (lane >> 1) & 1;
            float np[4];
            #pragma unroll
            for (int i = 0; i < 4; ++i) {
                float send = sel ? p[i] : p[i + 4];
                float recv = __shfl_xor(send, 2, 64);
                np[i] = (sel ? p[i + 4] : p[i]) + recv;
            }
            #pragma unroll
            for (int i = 0; i < 4; ++i) p[i] = np[i];
        }
        { // 4 -> 2 (xor 4)
            const bool sel = (lane >> 2) & 1;
            float np[2];
            #pragma unroll
            for (int i = 0; i < 2; ++i) {
                float send = sel ? p[i] : p[i + 2];
                float recv = __shfl_xor(send, 4, 64);
                np[i] = (sel ? p[i + 2] : p[i]) + recv;
            }
            p[0] = np[0]; p[1] = np[1];
        }
        { // 2 -> 1 (xor 8)
            const bool sel = (lane >> 3) & 1;
            float send = sel ? p[0] : p[1];
            float recv = __shfl_xor(send, 8, 64);
            p[0] = (sel ? p[1] : p[0]) + recv;
        }
    }
    // Finish across the four 16-lane groups (bits 4,5).
    p[0] += __shfl_xor(p[0], 16, 64);
    p[0] += __shfl_xor(p[0], 32, 64);

    const int g = lane & 15;
    const int j = ((g & 1) << 3) | ((g & 2) << 1) | ((g & 4) >> 1) | ((g & 8) >> 3);
    const float dot = p[0];

    float numer_c = 0.f, den_c = 0.f;
    if ((lane >> 4) == 0) {
        numer_c = (j >= 1 && j < W) ? dot : 0.f;
        int dup = 0;
        if (j < W) {
            const int idxj = walk[j];        // L1-hit broadcast line
            #pragma unroll
            for (int i = 0; i < ROW - 1; ++i)
                dup |= (i < j) & (idx[i] == idxj);
        }
        den_c = dup ? 0.f : expf(dot);
    }

    #pragma unroll
    for (int d = 1; d < 64; d <<= 1) {
        numer_c += __shfl_xor(numer_c, d, 64);
        den_c   += __shfl_xor(den_c, d, 64);
    }

    __shared__ float sm[ROWS_PER_BLOCK];
    if (lane == 0)
        sm[wv] = valid ? ((float)l * logf(den_c) - numer_c) : 0.f;
    __syncthreads();
    if (tid == 0)
        partial[blockIdx.x] = sm[0] + sm[1] + sm[2] + sm[3];
}

// Single-wave deterministic reduce of per-block partials -> mean.
__global__ __launch_bounds__(64) void n2v_reduce_kernel(
    const float* __restrict__ partial,
    float* __restrict__ out,
    int n, int batch)
{
    const int lane = threadIdx.x;
    float acc = 0.f;
    for (int i = lane; i < n; i += 64) acc += partial[i];
    #pragma unroll
    for (int d = 1; d < 64; d <<= 1) acc += __shfl_xor(acc, d, 64);
    if (lane == 0) out[0] = acc / (float)batch;
}

extern "C" void kernel_launch(void* const* d_in, const int* in_sizes, int n_in,
                              void* d_out, int out_size, void* d_ws, size_t ws_size,
                              hipStream_t stream)
{
    const float* X  = (const float*)d_in[0];
    const int*   rw = (const int*)d_in[1];
    const int*   lp = (const int*)d_in[2];
    float* out = (float*)d_out;

    const int batch = in_sizes[1] / ROW;                              // 4096
    const int grid  = (batch + ROWS_PER_BLOCK - 1) / ROWS_PER_BLOCK;  // 1024
    float* partial = (float*)d_ws;

    n2v_row_kernel<<<grid, 256, 0, stream>>>(X, rw, lp, partial, batch);
    n2v_reduce_kernel<<<1, 64, 0, stream>>>(partial, out, grid, batch);
}

// Round 8
// 12.731 us; speedup vs baseline: 3.2004x; 1.2860x over previous
//
#include <hip/hip_runtime.h>
#include <hip/hip_bf16.h>

#define DIM 128
#define ROW 16
#define ROWS_PER_BLOCK 8   // 512 threads = 8 waves, one row per 64-lane wave

// One 64-lane wave per batch row. Lane holds floats [lane*2, lane*2+2) of each
// gathered 128-dim embedding (float2 = 8B/lane, 512B/row per instruction,
// fully coalesced). Two-dispatch structure (fusion attempts R4/R5 both
// regressed: cross-XCD visibility costs more than a dispatch).
__global__ __launch_bounds__(512) void n2v_row_kernel(
    const float* __restrict__ X,
    const int* __restrict__ rw,
    const int* __restrict__ lp,
    float* __restrict__ partial,
    int batch)
{
    const int tid  = threadIdx.x;
    const int lane = tid & 63;
    const int wv   = tid >> 6;
    const int row  = blockIdx.x * ROWS_PER_BLOCK + wv;
    const bool valid = (row < batch);

    const int l = *lp;
    const int W = l + 1;                     // 6

    const int* walk = rw + (valid ? row : 0) * ROW;

    // 16 walk indices via 4 broadcast int4 loads (one 64B line).
    int idx[ROW];
    {
        int4 t0 = *reinterpret_cast<const int4*>(walk);
        int4 t1 = *reinterpret_cast<const int4*>(walk + 4);
        int4 t2 = *reinterpret_cast<const int4*>(walk + 8);
        int4 t3 = *reinterpret_cast<const int4*>(walk + 12);
        idx[0]=t0.x; idx[1]=t0.y; idx[2]=t0.z; idx[3]=t0.w;
        idx[4]=t1.x; idx[5]=t1.y; idx[6]=t1.z; idx[7]=t1.w;
        idx[8]=t2.x; idx[9]=t2.y; idx[10]=t2.z; idx[11]=t2.w;
        idx[12]=t3.x; idx[13]=t3.y; idx[14]=t3.z; idx[15]=t3.w;
    }

    // Gather: 16 float2 loads (512B/row/instruction, coalesced), all in flight.
    float2 e[ROW];
    #pragma unroll
    for (int j = 0; j < ROW; ++j) {
        e[j] = *reinterpret_cast<const float2*>(
            X + (size_t)idx[j] * DIM + lane * 2);
    }

    const float2 s = e[0];

    float p[ROW];
    #pragma unroll
    for (int j = 0; j < ROW; ++j)
        p[j] = e[j].x * s.x + e[j].y * s.y;

    // Value-halving butterfly over bits 0..3 (15 shfls); lane ends with the
    // 16-lane-group partial of dot[brev4(lane&15)].
    {
        { // 16 -> 8 (xor 1)
            const bool sel = (lane >> 0) & 1;
            float np[8];
            #pragma unroll
            for (int i = 0; i < 8; ++i) {
                float send = sel ? p[i] : p[i + 8];
                float recv = __shfl_xor(send, 1, 64);
                np[i] = (sel ? p[i + 8] : p[i]) + recv;
            }
            #pragma unroll
            for (int i = 0; i < 8; ++i) p[i] = np[i];
        }
        { // 8 -> 4 (xor 2)
            const bool sel = (lane >> 1) & 1;
            float np[4];
            #pragma unroll
            for (int i = 0; i < 4; ++i) {
                float send = sel ? p[i] : p[i + 4];
                float recv = __shfl_xor(send, 2, 64);
                np[i] = (sel ? p[i + 4] : p[i]) + recv;
            }
            #pragma unroll
            for (int i = 0; i < 4; ++i) p[i] = np[i];
        }
        { // 4 -> 2 (xor 4)
            const bool sel = (lane >> 2) & 1;
            float np[2];
            #pragma unroll
            for (int i = 0; i < 2; ++i) {
                float send = sel ? p[i] : p[i + 2];
                float recv = __shfl_xor(send, 4, 64);
                np[i] = (sel ? p[i + 2] : p[i]) + recv;
            }
            p[0] = np[0]; p[1] = np[1];
        }
        { // 2 -> 1 (xor 8)
            const bool sel = (lane >> 3) & 1;
            float send = sel ? p[0] : p[1];
            float recv = __shfl_xor(send, 8, 64);
            p[0] = (sel ? p[1] : p[0]) + recv;
        }
    }
    // Finish across the four 16-lane groups (bits 4,5).
    p[0] += __shfl_xor(p[0], 16, 64);
    p[0] += __shfl_xor(p[0], 32, 64);

    const int g = lane & 15;
    const int j = ((g & 1) << 3) | ((g & 2) << 1) | ((g & 4) >> 1) | ((g & 8) >> 3);
    const float dot = p[0];

    float numer_c = 0.f, den_c = 0.f;
    if ((lane >> 4) == 0) {
        numer_c = (j >= 1 && j < W) ? dot : 0.f;
        int dup = 0;
        if (j < W) {
            const int idxj = walk[j];        // L1-hit broadcast line
            #pragma unroll
            for (int i = 0; i < ROW - 1; ++i)
                dup |= (i < j) & (idx[i] == idxj);
        }
        den_c = dup ? 0.f : expf(dot);
    }

    #pragma unroll
    for (int d = 1; d < 64; d <<= 1) {
        numer_c += __shfl_xor(numer_c, d, 64);
        den_c   += __shfl_xor(den_c, d, 64);
    }

    __shared__ float sm[ROWS_PER_BLOCK];
    if (lane == 0)
        sm[wv] = valid ? ((float)l * logf(den_c) - numer_c) : 0.f;
    __syncthreads();
    if (tid == 0) {
        float bp = 0.f;
        #pragma unroll
        for (int i = 0; i < ROWS_PER_BLOCK; ++i) bp += sm[i];
        partial[blockIdx.x] = bp;
    }
}

// Single-block deterministic reduce of per-block partials -> mean.
__global__ __launch_bounds__(256) void n2v_reduce_kernel(
    const float* __restrict__ partial,
    float* __restrict__ out,
    int n, int batch)
{
    float acc = 0.f;
    for (int i = threadIdx.x; i < n; i += 256) acc += partial[i];
    #pragma unroll
    for (int d = 1; d < 64; d <<= 1) acc += __shfl_xor(acc, d, 64);
    __shared__ float sm[4];
    if ((threadIdx.x & 63) == 0) sm[threadIdx.x >> 6] = acc;
    __syncthreads();
    if (threadIdx.x == 0)
        out[0] = (sm[0] + sm[1] + sm[2] + sm[3]) / (float)batch;
}

extern "C" void kernel_launch(void* const* d_in, const int* in_sizes, int n_in,
                              void* d_out, int out_size, void* d_ws, size_t ws_size,
                              hipStream_t stream)
{
    const float* X  = (const float*)d_in[0];
    const int*   rw = (const int*)d_in[1];
    const int*   lp = (const int*)d_in[2];
    float* out = (float*)d_out;

    const int batch = in_sizes[1] / ROW;                              // 4096
    const int grid  = (batch + ROWS_PER_BLOCK - 1) / ROWS_PER_BLOCK;  // 512
    float* partial = (float*)d_ws;

    n2v_row_kernel<<<grid, 512, 0, stream>>>(X, rw, lp, partial, batch);
    n2v_reduce_kernel<<<1, 256, 0, stream>>>(partial, out, grid, batch);
}